// Round 9
// baseline (145.145 us; speedup 1.0000x reference)
//
#include <hip/hip_runtime.h>

// Problem: B=8, T=512, D=512, MAX_LEN = T*15 = 7680. Dtypes per reference
// (confirmed R0-R7): features fp32 (B,T,D), durations int32 (B,T),
// output fp32 (B,MAX_LEN,D). R7 passed (absmax 0) at dur_us=145 (incl.
// harness poison fills at 6.7 TB/s).
// R9 = R8 with compile fix: __builtin_nontemporal_store needs a clang
// native vector type, not HIP_vector_type<float,4>.
// R8 changes: (1) each 128-lane group owns 15 CONSECUTIVE frames -> one
// 10-step search per group, then idx advances <=1/frame (cum strictly
// increasing since dur>=1) == single LDS check per frame; (2) feature row
// kept in registers across frames with equal idx (mean reuse ~7.6x, cuts
// L2 gather traffic 126->~17 MB); (3) nontemporal stores (output never
// re-read; keep L2 for features).
#define BB 8
#define TT 512
#define DD 512
#define MAX_LEN 7680
#define FPG 15                        // frames per 128-lane group
#define FPB 30                        // frames per block (2 groups)
#define BPB (MAX_LEN / FPB)           // 256 blocks per batch

typedef float vfloat4 __attribute__((ext_vector_type(4)));

__global__ __launch_bounds__(256) void regulate_kernel(
    const vfloat4* __restrict__ feat,  // (B, T, DD/4) as float4
    const int2*    __restrict__ dur2,  // (B, T/2) as int2
    vfloat4*       __restrict__ out)   // (B, MAX_LEN, DD/4) as float4
{
    __shared__ int cum[TT];            // inclusive cumsum of clamped durations
    __shared__ int ps[256];            // pair partial sums for the scan

    const int t    = threadIdx.x;
    const int b    = blockIdx.x / BPB;
    const int base = (blockIdx.x % BPB) * FPB;

    // ---- load 2 durations/thread, clamp(min=1), pairwise inclusive scan ----
    int2 dd = dur2[b * (TT / 2) + t];
    int d0 = dd.x < 1 ? 1 : dd.x;
    int d1 = dd.y < 1 ? 1 : dd.y;
    ps[t] = d0 + d1;
    __syncthreads();
#pragma unroll
    for (int off = 1; off < 256; off <<= 1) {
        int x = (t >= off) ? ps[t - off] : 0;
        __syncthreads();
        ps[t] += x;
        __syncthreads();
    }
    int incl = ps[t];                  // sum of pairs 0..t == cum[2t+1]
    cum[2 * t]     = incl - d1;
    cum[2 * t + 1] = incl;
    __syncthreads();

    const int total = cum[TT - 1];
    const int lane  = t & 127;         // 128 lanes x float4 = one 2 KB row
    const int sub   = t >> 7;          // group id: frames are consecutive
    const int n0    = base + sub * FPG;

    // ---- one searchsorted_right(cum, n0) per group (10 steps, 513 answers)
    int lo = 0;
    {
        int hi = TT;
#pragma unroll
        for (int s = 0; s < 10; ++s) {
            int mid = (lo + hi) >> 1;
            if (cum[mid] <= n0) lo = mid + 1; else hi = mid;
        }
    }
    vfloat4 zero = {0.f, 0.f, 0.f, 0.f};
    vfloat4 cur  = zero;
    if (n0 < total)                    // n0 < total guarantees lo <= TT-1
        cur = feat[(size_t)(b * TT + lo) * (DD / 4) + lane];

    // ---- walk 15 consecutive frames; idx advances <= 1 per frame ----
#pragma unroll
    for (int i = 0; i < FPG; ++i) {
        const int n = n0 + i;
        if (i > 0) {
            if (n < total) {
                // invariant: cum[lo] > n-1; advance iff cum[lo] == n
                if (cum[lo] <= n) {
                    ++lo;              // strict monotonicity: new cum[lo] > n
                    cur = feat[(size_t)(b * TT + lo) * (DD / 4) + lane];
                }
            } else {
                cur = zero;
            }
        }
        __builtin_nontemporal_store(cur,
            &out[((size_t)b * MAX_LEN + n) * (DD / 4) + lane]);
    }
}

extern "C" void kernel_launch(void* const* d_in, const int* in_sizes, int n_in,
                              void* d_out, int out_size, void* d_ws, size_t ws_size,
                              hipStream_t stream) {
    // Select pointers by element count (features = B*T*D = 2097152, dur = 4096)
    const float* feat;
    const int*   dur;
    if (in_sizes[0] == BB * TT) {
        dur  = (const int*)d_in[0];
        feat = (const float*)d_in[1];
    } else {
        feat = (const float*)d_in[0];
        dur  = (const int*)d_in[1];
    }
    float* out = (float*)d_out;        // (B, MAX_LEN, D) fp32

    regulate_kernel<<<BB * BPB, 256, 0, stream>>>(
        (const vfloat4*)feat, (const int2*)dur, (vfloat4*)out);
}